// Round 5
// baseline (645.383 us; speedup 1.0000x reference)
//
#include <hip/hip_runtime.h>

// Problem constants: B=4, L=64, C=64, H=32, W=32
// BL = 256, HW = 1024, CHW = 65536, NIMG = B*L*C = 16384, NELEM = 16777216

#define NELEM 16777216
#define NIMG  16384

// ---------------- fully-unrolled register FFT-32 (radix-2 DIT) ----------------
template <bool INV>
__device__ __forceinline__ void fft32(float2 v[32]) {
  // bit-reverse permutation (5 bits)
#define SW(a, b) { float2 t_ = v[a]; v[a] = v[b]; v[b] = t_; }
  SW(1, 16) SW(2, 8)  SW(3, 24) SW(5, 20) SW(6, 12) SW(7, 28)
  SW(9, 18) SW(11, 26) SW(13, 22) SW(15, 30) SW(19, 25) SW(23, 29)
#undef SW
  constexpr float TC[16] = {
      1.0f, 0.9807852804032304f, 0.9238795325112867f, 0.8314696123025452f,
      0.7071067811865476f, 0.5555702330196022f, 0.3826834323650898f, 0.1950903220161283f,
      0.0f, -0.1950903220161283f, -0.3826834323650898f, -0.5555702330196022f,
      -0.7071067811865476f, -0.8314696123025452f, -0.9238795325112867f, -0.9807852804032304f};
  constexpr float TS[16] = {
      0.0f, 0.1950903220161283f, 0.3826834323650898f, 0.5555702330196022f,
      0.7071067811865476f, 0.8314696123025452f, 0.9238795325112867f, 0.9807852804032304f,
      1.0f, 0.9807852804032304f, 0.9238795325112867f, 0.8314696123025452f,
      0.7071067811865476f, 0.5555702330196022f, 0.3826834323650898f, 0.1950903220161283f};
#pragma unroll
  for (int s = 1; s <= 5; ++s) {
    const int len = 1 << s, half = len >> 1, tstep = 32 >> s;
#pragma unroll
    for (int i = 0; i < 32; i += len) {
#pragma unroll
      for (int j = 0; j < half; ++j) {
        const int k = j * tstep;
        const float wr = TC[k];
        const float wi = INV ? TS[k] : -TS[k];
        float2 b = v[i + j + half];
        float tr = wr * b.x - wi * b.y;
        float ti = wr * b.y + wi * b.x;
        float2 a = v[i + j];
        v[i + j] = make_float2(a.x + tr, a.y + ti);
        v[i + j + half] = make_float2(a.x - tr, a.y - ti);
      }
    }
  }
}

// ---------------- K1: channel mix (real x, complex Wb) -> A ----------------
__global__ __launch_bounds__(256) void kmix_b(const float* __restrict__ x,
                                              float2* __restrict__ A,
                                              const float* __restrict__ Wr,
                                              const float* __restrict__ Wi) {
  __shared__ float2 w[4096];
  const int t = threadIdx.x;
#pragma unroll
  for (int k = 0; k < 16; ++k) {
    int n = t + k * 256;
    w[n] = make_float2(Wr[n], Wi[n]);
  }
  __syncthreads();
  const int bl = blockIdx.x >> 2;
  const int pos = ((blockIdx.x & 3) << 8) + t;
  const int base = bl * 65536;
  float2 acc[64];
#pragma unroll
  for (int o = 0; o < 64; ++o) acc[o] = make_float2(0.f, 0.f);
  for (int c = 0; c < 64; ++c) {
    float xv = x[base + c * 1024 + pos];
#pragma unroll
    for (int o = 0; o < 64; ++o) {
      float2 wv = w[o * 64 + c];
      acc[o].x += wv.x * xv;
      acc[o].y += wv.y * xv;
    }
  }
#pragma unroll
  for (int o = 0; o < 64; ++o) A[base + o * 1024 + pos] = acc[o];
}

// ---------------- K2: forward FFT2 per (b,l,c) image, epilogue (+bb)*gamma ----------------
__global__ __launch_bounds__(128) void kfft_fwd(float2* __restrict__ A,
                                                const float* __restrict__ pl,
                                                const float* __restrict__ bbr,
                                                const float* __restrict__ bbi) {
  __shared__ float2 tile[4 * 1056];  // 4 images, rows padded to 33 float2
  const int t = threadIdx.x;
  const int imgBase = blockIdx.x * 4096;  // float2 elements
#pragma unroll
  for (int k = 0; k < 32; ++k) {
    int n = t + k * 128;
    float2 v = A[imgBase + n];
    int img = n >> 10, rem = n & 1023;
    tile[img * 1056 + (rem >> 5) * 33 + (rem & 31)] = v;
  }
  __syncthreads();
  const int img = t >> 5, lane = t & 31;
  {
    float2 v[32];
    float2* row = &tile[img * 1056 + lane * 33];
#pragma unroll
    for (int j = 0; j < 32; ++j) v[j] = row[j];
    fft32<false>(v);
#pragma unroll
    for (int j = 0; j < 32; ++j) row[j] = v[j];
  }
  __syncthreads();
  {
    float2 v[32];
    float2* col = &tile[img * 1056 + lane];
#pragma unroll
    for (int j = 0; j < 32; ++j) v[j] = col[j * 33];
    fft32<false>(v);
#pragma unroll
    for (int j = 0; j < 32; ++j) col[j * 33] = v[j];
  }
  __syncthreads();
#pragma unroll
  for (int k = 0; k < 32; ++k) {
    int n = t + k * 128;
    int img2 = n >> 10, rem = n & 1023, r = rem >> 5, cc = rem & 31;
    int gimg = blockIdx.x * 4 + img2;
    int ch = gimg & 63;
    float2 v = tile[img2 * 1056 + r * 33 + cc];
    float g = expf(pl[(128 + ch) * 32 + r]);
    v.x = (v.x + bbr[ch]) * g;
    v.y = (v.y + bbi[ch]) * g;
    A[imgBase + n] = v;
  }
}

// ---------------- K3: linear recurrence over L, save last hidden ----------------
// MODE 0: out1 is real-part-only float array (tail == 262144 floats)
// MODE 1: out1 is interleaved complex (re,im) float2 array (tail == 524288 floats)
template <int MODE>
__global__ __launch_bounds__(256) void kscan(float2* __restrict__ A,
                                             const float* __restrict__ pl,
                                             float* __restrict__ out1) {
  const int gid = blockIdx.x * 256 + threadIdx.x;  // 0..262143  = (b, c, h, w)
  const int chw = gid & 65535;
  const int b = gid >> 16;
  const int c = chw >> 10, hh = (chw >> 5) & 31;
  const float nu = expf(pl[c * 32 + hh]);
  const float th = expf(pl[2048 + c * 32 + hh]);
  const float rad = expf(-nu);
  const float lr = rad * cosf(th);
  const float li = rad * sinf(th);
  const int base = b * 4194304 + chw;  // b * L*CHW
  float2 h = A[base];
#pragma unroll 4
  for (int l = 1; l < 64; ++l) {
    float2 v = A[base + l * 65536];
    float hx = lr * h.x - li * h.y + v.x;
    float hy = lr * h.y + li * h.x + v.y;
    h = make_float2(hx, hy);
    A[base + l * 65536] = h;
  }
  if (MODE == 0) {
    out1[gid] = h.x;  // real part only
  } else {
    ((float2*)out1)[gid] = h;  // interleaved complex64
  }
}

// ---------------- K4: channel mix with Wc in frequency domain (in place) ----------------
__global__ __launch_bounds__(256) void kmix_c(float2* __restrict__ A,
                                              const float* __restrict__ Wr,
                                              const float* __restrict__ Wi) {
  __shared__ float2 w[4096];
  const int t = threadIdx.x;
#pragma unroll
  for (int k = 0; k < 16; ++k) {
    int n = t + k * 256;
    w[n] = make_float2(Wr[n], Wi[n]);
  }
  __syncthreads();
  const int bl = blockIdx.x >> 2;
  const int pos = ((blockIdx.x & 3) << 8) + t;
  const int base = bl * 65536;
  float2 acc[64];
#pragma unroll
  for (int o = 0; o < 64; ++o) acc[o] = make_float2(0.f, 0.f);
  for (int c = 0; c < 64; ++c) {
    float2 v = A[base + c * 1024 + pos];
#pragma unroll
    for (int o = 0; o < 64; ++o) {
      float2 wv = w[o * 64 + c];
      acc[o].x += wv.x * v.x - wv.y * v.y;
      acc[o].y += wv.x * v.y + wv.y * v.x;
    }
  }
#pragma unroll
  for (int o = 0; o < 64; ++o) A[base + o * 1024 + pos] = acc[o];
}

// ---------------- K5: inverse FFT2 + bc + real + LayerNorm + residual ----------------
__global__ __launch_bounds__(128) void kfft_inv_ln(const float2* __restrict__ A,
                                                   const float* __restrict__ x,
                                                   const float* __restrict__ bcr,
                                                   const float* __restrict__ lnw,
                                                   const float* __restrict__ lnb,
                                                   float* __restrict__ out0) {
  __shared__ float2 tile[4 * 1056];
  const int t = threadIdx.x;
  const int imgBase = blockIdx.x * 4096;
#pragma unroll
  for (int k = 0; k < 32; ++k) {
    int n = t + k * 128;
    float2 v = A[imgBase + n];
    int img = n >> 10, rem = n & 1023;
    tile[img * 1056 + (rem >> 5) * 33 + (rem & 31)] = v;
  }
  __syncthreads();
  const int img = t >> 5, lane = t & 31;
  {
    float2 v[32];
    float2* row = &tile[img * 1056 + lane * 33];
#pragma unroll
    for (int j = 0; j < 32; ++j) v[j] = row[j];
    fft32<true>(v);
#pragma unroll
    for (int j = 0; j < 32; ++j) row[j] = v[j];
  }
  __syncthreads();
  float2 v[32];
  {
    float2* col = &tile[img * 1056 + lane];
#pragma unroll
    for (int j = 0; j < 32; ++j) v[j] = col[j * 33];
    fft32<true>(v);
  }
  const int gimg = blockIdx.x * 4 + img;
  const int ch = gimg & 63;
  const float bc = bcr[ch];
  float rr[32];
  float s1 = 0.f, s2 = 0.f;
#pragma unroll
  for (int r = 0; r < 32; ++r) {
    rr[r] = v[r].x * (1.0f / 1024.0f) + bc;
    s1 += rr[r];
    s2 += rr[r] * rr[r];
  }
#pragma unroll
  for (int m = 1; m < 32; m <<= 1) {
    s1 += __shfl_xor(s1, m, 64);
    s2 += __shfl_xor(s2, m, 64);
  }
  const float mu = s1 * (1.0f / 1024.0f);
  const float var = s2 * (1.0f / 1024.0f) - mu * mu;
  const float rs = rsqrtf(var + 1e-5f);
  const int obase = gimg * 1024;
#pragma unroll
  for (int r = 0; r < 32; ++r) {
    int sp = r * 32 + lane;
    out0[obase + sp] = (rr[r] - mu) * rs * lnw[sp] + lnb[sp] + x[obase + sp];
  }
}

extern "C" void kernel_launch(void* const* d_in, const int* in_sizes, int n_in,
                              void* d_out, int out_size, void* d_ws, size_t ws_size,
                              hipStream_t stream) {
  const float* x   = (const float*)d_in[0];
  const float* pl  = (const float*)d_in[1];
  const float* Wbr = (const float*)d_in[2];
  const float* Wbi = (const float*)d_in[3];
  const float* bbr = (const float*)d_in[4];
  const float* bbi = (const float*)d_in[5];
  const float* Wcr = (const float*)d_in[6];
  const float* Wci = (const float*)d_in[7];
  const float* bcr = (const float*)d_in[8];
  // d_in[9] = bc_i: dropped by taking real part
  const float* lnw = (const float*)d_in[10];
  const float* lnb = (const float*)d_in[11];

  float* out0 = (float*)d_out;
  float* out1 = (float*)d_out + NELEM;  // tail: last_hidden_out
  float2* A = (float2*)d_ws;            // 16,777,216 complex = 134 MB

  const int tail = out_size - NELEM;

  kmix_b<<<1024, 256, 0, stream>>>(x, A, Wbr, Wbi);
  kfft_fwd<<<4096, 128, 0, stream>>>(A, pl, bbr, bbi);
  if (tail == 262144) {
    kscan<0><<<1024, 256, 0, stream>>>(A, pl, out1);  // real part only
  } else {
    kscan<1><<<1024, 256, 0, stream>>>(A, pl, out1);  // interleaved complex
  }
  kmix_c<<<1024, 256, 0, stream>>>(A, Wcr, Wci);
  kfft_inv_ln<<<4096, 128, 0, stream>>>(A, x, bcr, lnw, lnb, out0);
}